// Round 8
// baseline (251.698 us; speedup 1.0000x reference)
//
#include <hip/hip_runtime.h>

#define Bn 32
#define Cn 64
#define Hn 64
#define Wn 64
#define On 128
#define HP 62
#define WP 62
#define CKn 576
#define Ln (HP*WP)          // 3844
#define Y_ELEMS (Bn*On*Ln)  // 15745024

typedef unsigned int uint32;
typedef unsigned short ushort16;
typedef __bf16 bf16x8 __attribute__((ext_vector_type(8)));
typedef float floatx4 __attribute__((ext_vector_type(4)));

static __device__ __forceinline__ uint32 bf16r(float f){
  uint32 u = __float_as_uint(f);
  return (u + 0x7FFFu + ((u >> 16) & 1u)) >> 16;
}

// ---------------- new-path ws layout (floats) ----------------
#define KSB   4
#define GSZ   (On*CKn)            // 73728
#define NS1   0
#define NS2   128
#define NG    256                 // KSB * GSZ floats = 294912
#define NWNB  (NG + KSB*GSZ)      // 295168
#define NXB   (NWNB + 36864)      // 332032
#define NPB   (NXB + 4194304)     // 4526336  (proven-safe layout)
#define WS_NEED ((size_t)49800000)

__global__ __launch_bounds__(256) void k_norm(const float* __restrict__ w, ushort16* __restrict__ wnb,
                                              float* __restrict__ S1, float* __restrict__ S2,
                                              float* __restrict__ G, int ngbuf){
  int o = blockIdx.x; int t = threadIdx.x;
  for (int kq = 0; kq < ngbuf; kq++)
    for (int k = t; k < CKn; k += 256) G[(size_t)kq*GSZ + o*CKn + k] = 0.f;
  if (t == 0){ S1[o] = 0.f; S2[o] = 0.f; }
  float s = 0.f;
  for (int k = t; k < CKn; k += 256){ float v = w[o*CKn + k]; s += v*v; }
  #pragma unroll
  for (int off = 32; off; off >>= 1) s += __shfl_down(s, off);
  __shared__ float red[4]; __shared__ float sh_inv;
  if ((t & 63) == 0) red[t >> 6] = s;
  __syncthreads();
  if (t == 0){
    float tot = red[0] + red[1] + red[2] + red[3];
    float nrm = sqrtf(tot);
    sh_inv = (nrm == 0.f) ? 1.f : 1.f/nrm;
  }
  __syncthreads();
  float inv = sh_inv;
  for (int k = t; k < CKn; k += 256){
    float v = w[o*CKn + k] * inv;
    int c = k / 9;
    int q = k - c*9;
    wnb[o*CKn + q*64 + c] = (ushort16)bf16r(v);
  }
}

// x fp32 -> bf16, layout unchanged [b][c][h][w]
__global__ __launch_bounds__(256) void k_xb(const float* __restrict__ x, ushort16* __restrict__ xb){
  size_t idx = ((size_t)blockIdx.x*256 + threadIdx.x)*4;
  float4 v = *(const float4*)(x + idx);
  uint2 o;
  o.x = bf16r(v.x) | (bf16r(v.y) << 16);
  o.y = bf16r(v.z) | (bf16r(v.w) << 16);
  *(uint2*)(xb + idx) = o;
}

// MFMA implicit-GEMM conv with coalesced LDS-transpose epilogue (R5 win).
__global__ __launch_bounds__(256, 3) void k_convm(const float* __restrict__ x,
                                                  const ushort16* __restrict__ wnb,
                                                  const float* __restrict__ bias,
                                                  float* __restrict__ y){
  __shared__ ushort16 slab[4*64*68];
  __shared__ ushort16 Bl[2][128*36];
  int t = threadIdx.x;
  int lane = t & 63;
  int wv = t >> 6;
  int mtile = blockIdx.x;
  int b = blockIdx.y;
  int i0 = mtile*2;
  {
    int c0 = (t & 31)*2;
    int grp = t >> 5;
    int r = grp >> 1;
    int w0 = (grp & 1)*32;
    const float* p0 = x + (((size_t)b*Cn + c0)*Hn + (i0 + r))*Wn + w0;
    const float* p1 = p0 + (size_t)Hn*Wn;
    #pragma unroll
    for (int ch = 0; ch < 4; ch++){
      float4 A0 = *(const float4*)(p0 + ch*8);
      float4 A1 = *(const float4*)(p0 + ch*8 + 4);
      float4 B0 = *(const float4*)(p1 + ch*8);
      float4 B1 = *(const float4*)(p1 + ch*8 + 4);
      float v0[8] = {A0.x,A0.y,A0.z,A0.w,A1.x,A1.y,A1.z,A1.w};
      float v1[8] = {B0.x,B0.y,B0.z,B0.w,B1.x,B1.y,B1.z,B1.w};
      #pragma unroll
      for (int qq = 0; qq < 8; qq++){
        int wloc = w0 + ch*8 + qq;
        *(uint32*)&slab[(r*64 + wloc)*68 + c0] = (bf16r(v1[qq]) << 16) | bf16r(v0[qq]);
      }
    }
  }
  int ob = t >> 1;
  int kh16 = (t & 1)*16;
  const ushort16* wrow = wnb + (size_t)ob*CKn + kh16;
  {
    uint4 bA = *(const uint4*)(wrow);
    uint4 bB = *(const uint4*)(wrow + 8);
    ushort16* dst = &Bl[0][ob*36 + kh16];
    ((uint2*)dst)[0] = make_uint2(bA.x, bA.y);
    ((uint2*)dst)[1] = make_uint2(bA.z, bA.w);
    ((uint2*)dst)[2] = make_uint2(bB.x, bB.y);
    ((uint2*)dst)[3] = make_uint2(bB.z, bB.w);
  }
  int quad8 = (lane >> 4) << 3;
  int iT[2], jT[2];
  #pragma unroll
  for (int mt = 0; mt < 2; mt++){
    int m = wv*32 + mt*16 + (lane & 15);
    int pos = m < 124 ? m : 123;
    int hi = pos >= 62;
    iT[mt] = hi;
    jT[mt] = pos - (hi ? 62 : 0);
  }
  floatx4 acc[2][8];
  #pragma unroll
  for (int mt = 0; mt < 2; mt++)
    #pragma unroll
    for (int nt = 0; nt < 8; nt++)
      acc[mt][nt] = (floatx4){0.f, 0.f, 0.f, 0.f};
  union U8 { uint2 u[2]; bf16x8 v; };
  for (int s = 0; s < 18; s++){
    uint4 nA, nB;
    if (s < 17){
      nA = *(const uint4*)(wrow + (s+1)*32);
      nB = *(const uint4*)(wrow + (s+1)*32 + 8);
    }
    __syncthreads();
    int k0 = s*32 + quad8;
    int q = k0 >> 6;
    int c0 = k0 & 63;
    int kh = (q*86) >> 8;
    int kw = q - kh*3;
    bf16x8 af[2];
    #pragma unroll
    for (int mt = 0; mt < 2; mt++){
      const ushort16* ap = &slab[((iT[mt] + kh)*64 + jT[mt] + kw)*68 + c0];
      U8 ua;
      ua.u[0] = *(const uint2*)(ap);
      ua.u[1] = *(const uint2*)(ap + 4);
      af[mt] = ua.v;
    }
    const ushort16* bbase = &Bl[s & 1][(lane & 15)*36 + quad8];
    bf16x8 bf[8];
    #pragma unroll
    for (int nt = 0; nt < 8; nt++){
      const ushort16* bp = bbase + nt*576;
      U8 ub;
      ub.u[0] = *(const uint2*)(bp);
      ub.u[1] = *(const uint2*)(bp + 4);
      bf[nt] = ub.v;
    }
    #pragma unroll
    for (int mt = 0; mt < 2; mt++)
      #pragma unroll
      for (int nt = 0; nt < 8; nt++)
        acc[mt][nt] = __builtin_amdgcn_mfma_f32_16x16x32_bf16(af[mt], bf[nt], acc[mt][nt], 0, 0, 0);
    if (s < 17){
      ushort16* dst = &Bl[(s+1) & 1][ob*36 + kh16];
      ((uint2*)dst)[0] = make_uint2(nA.x, nA.y);
      ((uint2*)dst)[1] = make_uint2(nA.z, nA.w);
      ((uint2*)dst)[2] = make_uint2(nB.x, nB.y);
      ((uint2*)dst)[3] = make_uint2(nB.z, nB.w);
    }
  }
  float bv[8];
  #pragma unroll
  for (int nt = 0; nt < 8; nt++) bv[nt] = bias[nt*16 + (lane & 15)];
  // ---- coalesced epilogue via LDS transpose ----
  float* ytile = (float*)slab;            // 64 x 130 floats = 33280 B (slab is 34816 B)
  int cl = lane & 15;
  int quad = lane >> 4;
  #pragma unroll
  for (int chunk = 0; chunk < 2; chunk++){
    __syncthreads();
    #pragma unroll
    for (int nt4 = 0; nt4 < 4; nt4++){
      int nt = chunk*4 + nt4;
      int ol = nt4*16 + cl;
      #pragma unroll
      for (int mt = 0; mt < 2; mt++){
        #pragma unroll
        for (int reg = 0; reg < 4; reg++){
          int m = wv*32 + mt*16 + quad*4 + reg;
          if (m < 124) ytile[ol*130 + m] = acc[mt][nt][reg] + bv[nt];
        }
      }
    }
    __syncthreads();
    #pragma unroll
    for (int r = 0; r < 16; r++){
      int ol = wv*16 + r;
      int o = chunk*64 + ol;
      if (lane < 62){
        float2 v = *(float2*)&ytile[ol*130 + lane*2];
        *(float2*)&y[((size_t)b*On + o)*Ln + (size_t)i0*WP + lane*2] = v;
      }
    }
  }
}

// softmax v3: register-resident y (R6 win).
__global__ __launch_bounds__(256, 4) void k_softp(const float* __restrict__ y, ushort16* __restrict__ pb,
                                                  float* __restrict__ S1, float* __restrict__ S2){
  __shared__ float mpart[2][256], dpart[2][256];
  __shared__ float s1loc[128], s2loc[128];
  int b = blockIdx.x;
  int s = blockIdx.y;          // 0..30
  int i0 = s*2;
  int t = threadIdx.x;
  int j = t & 63;
  int og = t >> 6;
  if (t < 128){ s1loc[t] = 0.f; s2loc[t] = 0.f; }
  int je = j < WP ? j : (WP-1);
  const float* yb = y + ((size_t)b*On + og*32)*Ln + (size_t)i0*WP + je;
  float v0[32], v1[32];
  #pragma unroll
  for (int oi = 0; oi < 32; oi++){
    const float* yp = yb + (size_t)oi*Ln;
    v0[oi] = yp[0];
    v1[oi] = yp[WP];
  }
  float m0 = v0[0], m1 = v1[0];
  #pragma unroll
  for (int oi = 1; oi < 32; oi++){
    m0 = fmaxf(m0, v0[oi]);
    m1 = fmaxf(m1, v1[oi]);
  }
  float d0 = 0.f, d1 = 0.f;
  #pragma unroll
  for (int oi = 0; oi < 32; oi++){
    v0[oi] = __expf(v0[oi] - m0); d0 += v0[oi];
    v1[oi] = __expf(v1[oi] - m1); d1 += v1[oi];
  }
  mpart[0][t] = m0; dpart[0][t] = d0;
  mpart[1][t] = m1; dpart[1][t] = d1;
  __syncthreads();
  float scl[2];
  {
    float ml[2] = {m0, m1};
    #pragma unroll
    for (int r = 0; r < 2; r++){
      float ma = mpart[r][j],      mb = mpart[r][64+j];
      float mcc = mpart[r][128+j], md = mpart[r][192+j];
      float mm = fmaxf(fmaxf(ma, mb), fmaxf(mcc, md));
      float dd = dpart[r][j]*__expf(ma-mm) + dpart[r][64+j]*__expf(mb-mm)
               + dpart[r][128+j]*__expf(mcc-mm) + dpart[r][192+j]*__expf(md-mm);
      scl[r] = __expf(ml[r]-mm) / dd;
    }
  }
  bool act = j < WP;
  float sc0 = act ? scl[0] : 0.f;
  float sc1 = act ? scl[1] : 0.f;
  ushort16* ppb = pb + (((size_t)b*On + og*32)*HP + i0)*64 + j;
  #pragma unroll
  for (int oi = 0; oi < 32; oi++){
    float r0 = v0[oi]*sc0;
    float r1 = v1[oi]*sc1;
    float p0 = r0*r0, p1 = r1*r1;
    ushort16* pp = ppb + (size_t)oi*(HP*64);
    pp[0]  = (ushort16)bf16r(p0);
    pp[64] = (ushort16)bf16r(p1);
    float s1v = r0 + r1, s2v = p0 + p1;
    #pragma unroll
    for (int off = 32; off; off >>= 1){ s1v += __shfl_down(s1v, off); s2v += __shfl_down(s2v, off); }
    if (j == 0){ s1loc[og*32 + oi] += s1v; s2loc[og*32 + oi] += s2v; }
  }
  __syncthreads();
  if (t < 128){ atomicAdd(&S1[t], s1loc[t]); atomicAdd(&S2[t], s2loc[t]); }
}

// MFMA delta v7: 2 A-fragments per wave (o and o+64) against shared x fragments.
// R7 post-mortem: 1 vs 2 blocks/CU both 53us -> limiter is the per-CU LDS pipe
// (13.2M conflict cycles + issue ~= wall time). The 4 mgl-waves read identical
// x fragments (60 of 92 KB reads/iter redundant). Fix: fold the oh grid dim
// into the block: acc[2][9] per wave (o, o+64) reusing each x fragment for 2
// MFMAs. LDS/MFMA: 0.72 -> 0.47 KB. P-tile 2set x 128o (32KB, LDS 45.5KB).
// Epilogue: 2-pass ih-merge in LDS -> atomic count unchanged (4.7M, 16-way).
#define DOKH3(a0, a1, dc, ec, off) { \
  U16 f0, f1, f2; \
  f0.q = dc; \
  f1.q = make_uint4((dc.x>>16)|(dc.y<<16), (dc.y>>16)|(dc.z<<16), \
                    (dc.z>>16)|(dc.w<<16), (dc.w>>16)|(ec<<16)); \
  f2.q = make_uint4(dc.y, dc.z, dc.w, ec); \
  acc[0][(off)+0] = __builtin_amdgcn_mfma_f32_16x16x32_bf16(a0, f0.v, acc[0][(off)+0], 0, 0, 0); \
  acc[1][(off)+0] = __builtin_amdgcn_mfma_f32_16x16x32_bf16(a1, f0.v, acc[1][(off)+0], 0, 0, 0); \
  acc[0][(off)+1] = __builtin_amdgcn_mfma_f32_16x16x32_bf16(a0, f1.v, acc[0][(off)+1], 0, 0, 0); \
  acc[1][(off)+1] = __builtin_amdgcn_mfma_f32_16x16x32_bf16(a1, f1.v, acc[1][(off)+1], 0, 0, 0); \
  acc[0][(off)+2] = __builtin_amdgcn_mfma_f32_16x16x32_bf16(a0, f2.v, acc[0][(off)+2], 0, 0, 0); \
  acc[1][(off)+2] = __builtin_amdgcn_mfma_f32_16x16x32_bf16(a1, f2.v, acc[1][(off)+2], 0, 0, 0); \
}

__global__ __launch_bounds__(512, 1) void k_deltam(const ushort16* __restrict__ xb,
                                                   const ushort16* __restrict__ pb,
                                                   float* __restrict__ G){
  // LDS: P 2set*128row*128B = 32768 | x 2set*48row*144B = 13824 -> 46592 B
  __shared__ uint4 lds4[46592/16];
  char* ldsb = (char*)lds4;
  int t = threadIdx.x;
  int lane = t & 63;
  int wv = t >> 6;          // 0..7
  int mgl = wv & 3;
  int ih  = wv >> 2;
  int bx  = blockIdx.x;     // 0..7: ntk = bx&3, khalf = bx>>2
  int ntk = bx & 3;
  int khalf = bx >> 2;
  int b   = blockIdx.y;
  int it0 = khalf*16;
  int nit = khalf ? 15 : 16;
  int cl = lane & 15;
  int quad = lane >> 4;
  int quad8 = quad << 3;

  // ---- P staging: 2 threads/row, 4 granules (64 B) each ----
  int o256 = t >> 1;            // 0..255
  int sP = o256 >> 7;           // set (ih)
  int oP = o256 & 127;          // o row 0..127
  int segP = t & 1;             // half-row
  const ushort16* pbase = pb + ((size_t)b*On + oP)*(HP*64) + segP*32;
  int pIrow = sP*31 + it0;
  char* pwr = ldsb + (sP*128 + oP)*128;
  int psw[4];
  #pragma unroll
  for (int jj = 0; jj < 4; jj++) psw[jj] = ((4*segP + jj) ^ (oP & 7)) << 4;
  // ---- x staging (unchanged roles) ----
  int pX = t & 7;
  int r1 = t >> 3;
  int s1_ = (r1 >= 48) ? 1 : 0;
  int rr1 = r1 - s1_*48;
  int c1 = rr1/3, kh1 = rr1 - c1*3;
  int rr2 = (64 + (t >> 3)) - 48;
  int c2 = rr2/3, kh2 = rr2 - c2*3;
  const ushort16* xbb = xb + ((size_t)b*Cn + ntk*16)*(Hn*Wn) + pX*8;
  const ushort16* x1base = xbb + (size_t)c1*(Hn*Wn);
  const ushort16* x2base = xbb + (size_t)c2*(Hn*Wn);
  int x1Irow = s1_*31 + kh1 + it0;
  int x2Irow = 31 + kh2 + it0;
  char* x1wr = ldsb + 32768 + (s1_*48 + c1*3 + kh1)*144 + pX*16;
  char* x2wr = ldsb + 32768 + (48    + c2*3 + kh2)*144 + pX*16;

  if (t < 96) *(uint4*)(ldsb + 32768 + t*144 + 128) = make_uint4(0,0,0,0);

  const char* ptb = ldsb + ih*16384;
  const char* xtb = ldsb + 32768 + ih*6912;
  int orow = mgl*16 + cl;
  int o7 = cl & 7;

  floatx4 acc[2][9];
  #pragma unroll
  for (int h = 0; h < 2; h++)
    #pragma unroll
    for (int nt = 0; nt < 9; nt++) acc[h][nt] = (floatx4){0.f, 0.f, 0.f, 0.f};
  union U16 { uint4 q; bf16x8 v; };

  uint4 pr[4], xr0, xr1;
  {
    const ushort16* prow = pbase + (size_t)(pIrow + 0)*64;
    #pragma unroll
    for (int jj = 0; jj < 4; jj++) pr[jj] = *(const uint4*)(prow + jj*8);
    xr0 = *(const uint4*)(x1base + (size_t)(x1Irow + 0)*Wn);
    if (t < 256) xr1 = *(const uint4*)(x2base + (size_t)(x2Irow + 0)*Wn);
  }

  for (int it = 0; it < nit; ++it){
    __syncthreads();
    #pragma unroll
    for (int jj = 0; jj < 4; jj++) *(uint4*)(pwr + psw[jj]) = pr[jj];
    *(uint4*)(x1wr) = xr0;
    if (t < 256) *(uint4*)(x2wr) = xr1;
    if (it < nit-1){
      const ushort16* prow = pbase + (size_t)(pIrow + it + 1)*64;
      #pragma unroll
      for (int jj = 0; jj < 4; jj++) pr[jj] = *(const uint4*)(prow + jj*8);
      xr0 = *(const uint4*)(x1base + (size_t)(x1Irow + it + 1)*Wn);
      if (t < 256) xr1 = *(const uint4*)(x2base + (size_t)(x2Irow + it + 1)*Wn);
    }
    __syncthreads();
    #pragma unroll
    for (int sl = 0; sl < 2; sl++){
      int g16 = ((sl*4 + quad) ^ o7) << 4;
      U16 a0, a1;
      a0.q = *(const uint4*)(ptb + orow*128 + g16);
      a1.q = *(const uint4*)(ptb + (64 + orow)*128 + g16);
      #pragma unroll
      for (int kh = 0; kh < 3; kh++){
        const char* rb = xtb + (cl*3 + kh)*144;
        uint4 d = *(const uint4*)(rb + ((sl*32 + quad8) << 1));
        uint32 e = *(const uint32*)(rb + ((sl*32 + quad8 + 8) << 1));
        DOKH3(a0.v, a1.v, d, e, kh*3)
      }
    }
  }

  // ---- epilogue: per o-half, merge ih pairs in LDS then atomic ----
  float* sc = (float*)ldsb;          // 64*144 floats = 36864 B
  float* Gq = G + (size_t)(b & 3)*GSZ;
  #pragma unroll
  for (int half = 0; half < 2; half++){
    __syncthreads();                 // LDS free (compute done / prev pass done)
    if (ih == 1){
      #pragma unroll
      for (int nt = 0; nt < 9; nt++)
        #pragma unroll
        for (int reg = 0; reg < 4; reg++)
          sc[(mgl*16 + quad*4 + reg)*144 + nt*16 + cl] = acc[half][nt][reg];
    }
    __syncthreads();
    if (ih == 0){
      #pragma unroll
      for (int nt = 0; nt < 9; nt++)
        #pragma unroll
        for (int reg = 0; reg < 4; reg++){
          int ol = mgl*16 + quad*4 + reg;
          float v = acc[half][nt][reg] + sc[ol*144 + nt*16 + cl];
          atomicAdd(&Gq[(size_t)(half*64 + ol)*CKn + nt*64 + ntk*16 + cl], v);
        }
    }
  }
}

__global__ __launch_bounds__(576) void k_finalm(const float* __restrict__ w, const float* __restrict__ G,
                                                const float* __restrict__ S1, const float* __restrict__ S2,
                                                float* __restrict__ dw){
  int o = blockIdx.x; int k = threadIdx.x;
  int c = k / 9;
  int q = k - c*9;
  float s1 = S1[o]; if (s1 == 0.f) s1 = 1.f;
  float g = 0.f;
  #pragma unroll
  for (int kq = 0; kq < KSB; kq++) g += G[(size_t)kq*GSZ + o*CKn + q*64 + c];
  dw[o*CKn + k] = (g - S2[o]*w[o*CKn + k]) / s1;
}

// ---------------- old fallback path ----------------
__global__ __launch_bounds__(256) void k_soft_old(const float* __restrict__ y, float* __restrict__ mbuf,
                                                  float* __restrict__ invdbuf, float* __restrict__ S1,
                                                  float* __restrict__ S2){
  __shared__ float s1loc[128], s2loc[128];
  int t = threadIdx.x;
  if (t < 128){ s1loc[t] = 0.f; s2loc[t] = 0.f; }
  __syncthreads();
  int b = blockIdx.x;
  int i = blockIdx.y*4 + (t >> 6);
  int j = t & 63;
  bool act = (i < 62) && (j < 62);
  const float* yp = y + (((size_t)b*On)*HP + (i < 62 ? i : 0))*WP + j;
  float mx = -3.0e38f;
  if (act){ for (int o = 0; o < On; o++) mx = fmaxf(mx, yp[(size_t)o*Ln]); }
  float den = 0.f;
  if (act){ for (int o = 0; o < On; o++) den += __expf(yp[(size_t)o*Ln] - mx); }
  float inv = act ? 1.f/den : 0.f;
  if (act){
    int pos = (b*HP + i)*WP + j;
    mbuf[pos] = mx; invdbuf[pos] = inv;
  }
  for (int o = 0; o < On; o++){
    float r = act ? __expf(yp[(size_t)o*Ln] - mx)*inv : 0.f;
    float s1v = r, s2v = r*r;
    #pragma unroll
    for (int off = 32; off; off >>= 1){ s1v += __shfl_down(s1v, off); s2v += __shfl_down(s2v, off); }
    if ((t & 63) == 0){ atomicAdd(&s1loc[o], s1v); atomicAdd(&s2loc[o], s2v); }
  }
  __syncthreads();
  if (t < 128){ atomicAdd(&S1[t], s1loc[t]); atomicAdd(&S2[t], s2loc[t]); }
}

__global__ __launch_bounds__(256) void k_delta_old(const float* __restrict__ x, const float* __restrict__ y,
                                                   const float* __restrict__ mbuf, const float* __restrict__ invdbuf,
                                                   float* __restrict__ G){
  __shared__ float planes[3][64][64];
  __shared__ float plds[16][64];
  int o0 = blockIdx.x * 16;
  int bs = blockIdx.y;
  int b = bs >> 2;
  int s = bs & 3;
  int i0 = s * 16;
  int nrows = (s == 3) ? 14 : 16;
  int t = threadIdx.x;
  int lane = t & 63;
  int w = t >> 6;
  int lc = t >> 2;
  int lw0 = (t & 3) << 4;
  const float* xb = x + (size_t)b*(Cn*Hn*Wn) + (size_t)lc*(Hn*Wn) + lw0;
  float acc[4][9];
  #pragma unroll
  for (int oi = 0; oi < 4; oi++)
    #pragma unroll
    for (int q = 0; q < 9; q++) acc[oi][q] = 0.f;
  #pragma unroll
  for (int pp = 0; pp < 2; pp++){
    int ih = i0 + pp;
    const float* src = xb + (size_t)ih*Wn;
    #pragma unroll
    for (int q = 0; q < 16; q++) planes[ih % 3][lw0 + q][lc] = src[q];
  }
  for (int ii = 0; ii < nrows; ii++){
    int i = i0 + ii;
    {
      int ih = i + 2;
      const float* src = xb + (size_t)ih*Wn;
      #pragma unroll
      for (int q = 0; q < 16; q++) planes[ih % 3][lw0 + q][lc] = src[q];
    }
    int R = b*HP + i;
    #pragma unroll
    for (int oi = 0; oi < 4; oi++){
      int o = o0 + w*4 + oi;
      float p = 0.f;
      if (lane < WP){
        int pos = R*WP + lane;
        float yv = y[(((size_t)b*On + o)*HP + i)*WP + lane];
        float r = __expf(yv - mbuf[pos]) * invdbuf[pos];
        p = r*r;
      }
      plds[w*4 + oi][lane] = p;
    }
    __syncthreads();
    int c = lane;
    int s0 = i % 3, s1 = (i+1) % 3, s2g = (i+2) % 3;
    #pragma unroll 1
    for (int jj0 = 0; jj0 < 56; jj0 += 8){
      float xv[3][12];
      #pragma unroll
      for (int q = 0; q < 12; q++){
        xv[0][q] = planes[s0][jj0+q][c];
        xv[1][q] = planes[s1][jj0+q][c];
        xv[2][q] = planes[s2g][jj0+q][c];
      }
      #pragma unroll
      for (int oi = 0; oi < 4; oi++){
        float4 pa = *(const float4*)&plds[w*4+oi][jj0];
        float4 pbq = *(const float4*)&plds[w*4+oi][jj0+4];
        float pv[8] = {pa.x,pa.y,pa.z,pa.w,pbq.x,pbq.y,pbq.z,pbq.w};
        #pragma unroll
        for (int kh = 0; kh < 3; kh++)
          #pragma unroll
          for (int kw = 0; kw < 3; kw++)
            #pragma unroll
            for (int dj = 0; dj < 8; dj++)
              acc[oi][kh*3+kw] += pv[dj]*xv[kh][dj+kw];
      }
    }
    {
      float xv[3][12];
      #pragma unroll
      for (int q = 0; q < 12; q++){
        bool ok = (56 + q) < 64;
        xv[0][q] = ok ? planes[s0][56+q][c] : 0.f;
        xv[1][q] = ok ? planes[s1][56+q][c] : 0.f;
        xv[2][q] = ok ? planes[s2g][56+q][c] : 0.f;
      }
      #pragma unroll
      for (int oi = 0; oi < 4; oi++){
        float4 pa = *(const float4*)&plds[w*4+oi][56];
        float4 pbq = *(const float4*)&plds[w*4+oi][60];
        float pv[8] = {pa.x,pa.y,pa.z,pa.w,pbq.x,pbq.y,pbq.z,pbq.w};
        #pragma unroll
        for (int kh = 0; kh < 3; kh++)
          #pragma unroll
          for (int kw = 0; kw < 3; kw++)
            #pragma unroll
            for (int dj = 0; dj < 8; dj++)
              acc[oi][kh*3+kw] += pv[dj]*xv[kh][dj+kw];
      }
    }
    __syncthreads();
  }
  #pragma unroll
  for (int oi = 0; oi < 4; oi++){
    float* Gr = G + (size_t)(o0 + w*4 + oi)*CKn + lane*9;
    #pragma unroll
    for (int q = 0; q < 9; q++) atomicAdd(&Gr[q], acc[oi][q]);
  }
}

__global__ __launch_bounds__(576) void k_final_old(const float* __restrict__ w, const float* __restrict__ G,
                                                   const float* __restrict__ S1, const float* __restrict__ S2,
                                                   float* __restrict__ dw){
  int o = blockIdx.x; int k = threadIdx.x;
  float s1 = S1[o]; if (s1 == 0.f) s1 = 1.f;
  dw[o*CKn + k] = (G[o*CKn + k] - S2[o]*w[o*CKn + k]) / s1;
}

extern "C" void kernel_launch(void* const* d_in, const int* in_sizes, int n_in,
                              void* d_out, int out_size, void* d_ws, size_t ws_size,
                              hipStream_t stream){
  const float* x    = (const float*)d_in[0];
  const float* w    = (const float*)d_in[1];
  const float* bias = (const float*)d_in[2];
  float* y  = (float*)d_out;
  float* dw = (float*)d_out + Y_ELEMS;
  float* ws = (float*)d_ws;

  if (ws_size >= WS_NEED){
    float* S1 = ws + NS1;
    float* S2 = ws + NS2;
    float* G  = ws + NG;
    ushort16* wnb = (ushort16*)(ws + NWNB);
    ushort16* xb  = (ushort16*)(ws + NXB);
    ushort16* pb  = (ushort16*)(ws + NPB);
    k_norm  <<<dim3(On),      dim3(256), 0, stream>>>(w, wnb, S1, S2, G, KSB);
    k_xb    <<<dim3(8192),    dim3(256), 0, stream>>>(x, xb);
    k_convm <<<dim3(31, Bn),  dim3(256), 0, stream>>>(x, wnb, bias, y);
    k_softp <<<dim3(Bn, 31),  dim3(256), 0, stream>>>(y, pb, S1, S2);
    k_deltam<<<dim3(8, Bn),   dim3(512), 0, stream>>>(xb, pb, G);
    k_finalm<<<dim3(On),      dim3(CKn), 0, stream>>>(w, G, S1, S2, dw);
  } else {
    float* S1   = ws + 73728;
    float* S2   = ws + 73856;
    float* G    = ws + 73984;
    float* mbuf = ws + 147712;
    float* invd = ws + 270720;
    ushort16* wnb = (ushort16*)(ws + 393728);
    k_norm     <<<dim3(On),      dim3(256), 0, stream>>>(w, wnb, S1, S2, G, 1);
    k_convm    <<<dim3(31, Bn),  dim3(256), 0, stream>>>(x, wnb, bias, y);
    k_soft_old <<<dim3(Bn, 16),  dim3(256), 0, stream>>>(y, mbuf, invd, S1, S2);
    k_delta_old<<<dim3(8, Bn*4), dim3(256), 0, stream>>>(x, y, mbuf, invd, G);
    k_final_old<<<dim3(On),      dim3(CKn), 0, stream>>>(w, G, S1, S2, dw);
  }
}

// Round 9
// 209.638 us; speedup vs baseline: 1.2006x; 1.2006x over previous
//
#include <hip/hip_runtime.h>

#define Bn 32
#define Cn 64
#define Hn 64
#define Wn 64
#define On 128
#define HP 62
#define WP 62
#define CKn 576
#define Ln (HP*WP)          // 3844
#define Y_ELEMS (Bn*On*Ln)  // 15745024

typedef unsigned int uint32;
typedef unsigned short ushort16;
typedef __bf16 bf16x8 __attribute__((ext_vector_type(8)));
typedef float floatx4 __attribute__((ext_vector_type(4)));

static __device__ __forceinline__ uint32 bf16r(float f){
  uint32 u = __float_as_uint(f);
  return (u + 0x7FFFu + ((u >> 16) & 1u)) >> 16;
}

// ---------------- new-path ws layout (floats) ----------------
#define KSB   4
#define GSZ   (On*CKn)            // 73728
#define NS1   0
#define NS2   128
#define NG    256                 // KSB * GSZ floats = 294912
#define NWNB  (NG + KSB*GSZ)      // 295168
#define NXB   (NWNB + 36864)      // 332032
#define NPB   (NXB + 4194304)     // 4526336  (proven-safe layout)
#define WS_NEED ((size_t)49800000)

// fused: blocks 0..8191 = x->bf16 convert; blocks 8192..8319 = weight norm + G/S zero
__global__ __launch_bounds__(256) void k_normxb(const float* __restrict__ w, ushort16* __restrict__ wnb,
                                                float* __restrict__ S1, float* __restrict__ S2,
                                                float* __restrict__ G,
                                                const float* __restrict__ x, ushort16* __restrict__ xbo){
  __shared__ float red[4]; __shared__ float sh_inv;
  int bid = blockIdx.x;
  int t = threadIdx.x;
  if (bid < 8192){
    size_t idx = ((size_t)bid*256 + t)*4;
    float4 v = *(const float4*)(x + idx);
    uint2 o;
    o.x = bf16r(v.x) | (bf16r(v.y) << 16);
    o.y = bf16r(v.z) | (bf16r(v.w) << 16);
    *(uint2*)(xbo + idx) = o;
    return;
  }
  int o = bid - 8192;
  for (int kq = 0; kq < KSB; kq++)
    for (int k = t; k < CKn; k += 256) G[(size_t)kq*GSZ + o*CKn + k] = 0.f;
  if (t == 0){ S1[o] = 0.f; S2[o] = 0.f; }
  float s = 0.f;
  for (int k = t; k < CKn; k += 256){ float v = w[o*CKn + k]; s += v*v; }
  #pragma unroll
  for (int off = 32; off; off >>= 1) s += __shfl_down(s, off);
  if ((t & 63) == 0) red[t >> 6] = s;
  __syncthreads();
  if (t == 0){
    float tot = red[0] + red[1] + red[2] + red[3];
    float nrm = sqrtf(tot);
    sh_inv = (nrm == 0.f) ? 1.f : 1.f/nrm;
  }
  __syncthreads();
  float inv = sh_inv;
  for (int k = t; k < CKn; k += 256){
    float v = w[o*CKn + k] * inv;
    int c = k / 9;
    int q = k - c*9;
    wnb[o*CKn + q*64 + c] = (ushort16)bf16r(v);
  }
}

// standalone norm (fallback path)
__global__ __launch_bounds__(256) void k_norm(const float* __restrict__ w, ushort16* __restrict__ wnb,
                                              float* __restrict__ S1, float* __restrict__ S2,
                                              float* __restrict__ G, int ngbuf){
  int o = blockIdx.x; int t = threadIdx.x;
  for (int kq = 0; kq < ngbuf; kq++)
    for (int k = t; k < CKn; k += 256) G[(size_t)kq*GSZ + o*CKn + k] = 0.f;
  if (t == 0){ S1[o] = 0.f; S2[o] = 0.f; }
  float s = 0.f;
  for (int k = t; k < CKn; k += 256){ float v = w[o*CKn + k]; s += v*v; }
  #pragma unroll
  for (int off = 32; off; off >>= 1) s += __shfl_down(s, off);
  __shared__ float red[4]; __shared__ float sh_inv;
  if ((t & 63) == 0) red[t >> 6] = s;
  __syncthreads();
  if (t == 0){
    float tot = red[0] + red[1] + red[2] + red[3];
    float nrm = sqrtf(tot);
    sh_inv = (nrm == 0.f) ? 1.f : 1.f/nrm;
  }
  __syncthreads();
  float inv = sh_inv;
  for (int k = t; k < CKn; k += 256){
    float v = w[o*CKn + k] * inv;
    int c = k / 9;
    int q = k - c*9;
    wnb[o*CKn + q*64 + c] = (ushort16)bf16r(v);
  }
}

// MFMA implicit-GEMM conv with coalesced LDS-transpose epilogue (R5 win).
__global__ __launch_bounds__(256, 3) void k_convm(const float* __restrict__ x,
                                                  const ushort16* __restrict__ wnb,
                                                  const float* __restrict__ bias,
                                                  float* __restrict__ y){
  __shared__ ushort16 slab[4*64*68];
  __shared__ ushort16 Bl[2][128*36];
  int t = threadIdx.x;
  int lane = t & 63;
  int wv = t >> 6;
  int mtile = blockIdx.x;
  int b = blockIdx.y;
  int i0 = mtile*2;
  {
    int c0 = (t & 31)*2;
    int grp = t >> 5;
    int r = grp >> 1;
    int w0 = (grp & 1)*32;
    const float* p0 = x + (((size_t)b*Cn + c0)*Hn + (i0 + r))*Wn + w0;
    const float* p1 = p0 + (size_t)Hn*Wn;
    #pragma unroll
    for (int ch = 0; ch < 4; ch++){
      float4 A0 = *(const float4*)(p0 + ch*8);
      float4 A1 = *(const float4*)(p0 + ch*8 + 4);
      float4 B0 = *(const float4*)(p1 + ch*8);
      float4 B1 = *(const float4*)(p1 + ch*8 + 4);
      float v0[8] = {A0.x,A0.y,A0.z,A0.w,A1.x,A1.y,A1.z,A1.w};
      float v1[8] = {B0.x,B0.y,B0.z,B0.w,B1.x,B1.y,B1.z,B1.w};
      #pragma unroll
      for (int qq = 0; qq < 8; qq++){
        int wloc = w0 + ch*8 + qq;
        *(uint32*)&slab[(r*64 + wloc)*68 + c0] = (bf16r(v1[qq]) << 16) | bf16r(v0[qq]);
      }
    }
  }
  int ob = t >> 1;
  int kh16 = (t & 1)*16;
  const ushort16* wrow = wnb + (size_t)ob*CKn + kh16;
  {
    uint4 bA = *(const uint4*)(wrow);
    uint4 bB = *(const uint4*)(wrow + 8);
    ushort16* dst = &Bl[0][ob*36 + kh16];
    ((uint2*)dst)[0] = make_uint2(bA.x, bA.y);
    ((uint2*)dst)[1] = make_uint2(bA.z, bA.w);
    ((uint2*)dst)[2] = make_uint2(bB.x, bB.y);
    ((uint2*)dst)[3] = make_uint2(bB.z, bB.w);
  }
  int quad8 = (lane >> 4) << 3;
  int iT[2], jT[2];
  #pragma unroll
  for (int mt = 0; mt < 2; mt++){
    int m = wv*32 + mt*16 + (lane & 15);
    int pos = m < 124 ? m : 123;
    int hi = pos >= 62;
    iT[mt] = hi;
    jT[mt] = pos - (hi ? 62 : 0);
  }
  floatx4 acc[2][8];
  #pragma unroll
  for (int mt = 0; mt < 2; mt++)
    #pragma unroll
    for (int nt = 0; nt < 8; nt++)
      acc[mt][nt] = (floatx4){0.f, 0.f, 0.f, 0.f};
  union U8 { uint2 u[2]; bf16x8 v; };
  for (int s = 0; s < 18; s++){
    uint4 nA, nB;
    if (s < 17){
      nA = *(const uint4*)(wrow + (s+1)*32);
      nB = *(const uint4*)(wrow + (s+1)*32 + 8);
    }
    __syncthreads();
    int k0 = s*32 + quad8;
    int q = k0 >> 6;
    int c0 = k0 & 63;
    int kh = (q*86) >> 8;
    int kw = q - kh*3;
    bf16x8 af[2];
    #pragma unroll
    for (int mt = 0; mt < 2; mt++){
      const ushort16* ap = &slab[((iT[mt] + kh)*64 + jT[mt] + kw)*68 + c0];
      U8 ua;
      ua.u[0] = *(const uint2*)(ap);
      ua.u[1] = *(const uint2*)(ap + 4);
      af[mt] = ua.v;
    }
    const ushort16* bbase = &Bl[s & 1][(lane & 15)*36 + quad8];
    bf16x8 bf[8];
    #pragma unroll
    for (int nt = 0; nt < 8; nt++){
      const ushort16* bp = bbase + nt*576;
      U8 ub;
      ub.u[0] = *(const uint2*)(bp);
      ub.u[1] = *(const uint2*)(bp + 4);
      bf[nt] = ub.v;
    }
    #pragma unroll
    for (int mt = 0; mt < 2; mt++)
      #pragma unroll
      for (int nt = 0; nt < 8; nt++)
        acc[mt][nt] = __builtin_amdgcn_mfma_f32_16x16x32_bf16(af[mt], bf[nt], acc[mt][nt], 0, 0, 0);
    if (s < 17){
      ushort16* dst = &Bl[(s+1) & 1][ob*36 + kh16];
      ((uint2*)dst)[0] = make_uint2(nA.x, nA.y);
      ((uint2*)dst)[1] = make_uint2(nA.z, nA.w);
      ((uint2*)dst)[2] = make_uint2(nB.x, nB.y);
      ((uint2*)dst)[3] = make_uint2(nB.z, nB.w);
    }
  }
  float bv[8];
  #pragma unroll
  for (int nt = 0; nt < 8; nt++) bv[nt] = bias[nt*16 + (lane & 15)];
  // ---- coalesced epilogue via LDS transpose ----
  float* ytile = (float*)slab;            // 64 x 130 floats = 33280 B (slab is 34816 B)
  int cl = lane & 15;
  int quad = lane >> 4;
  #pragma unroll
  for (int chunk = 0; chunk < 2; chunk++){
    __syncthreads();
    #pragma unroll
    for (int nt4 = 0; nt4 < 4; nt4++){
      int nt = chunk*4 + nt4;
      int ol = nt4*16 + cl;
      #pragma unroll
      for (int mt = 0; mt < 2; mt++){
        #pragma unroll
        for (int reg = 0; reg < 4; reg++){
          int m = wv*32 + mt*16 + quad*4 + reg;
          if (m < 124) ytile[ol*130 + m] = acc[mt][nt][reg] + bv[nt];
        }
      }
    }
    __syncthreads();
    #pragma unroll
    for (int r = 0; r < 16; r++){
      int ol = wv*16 + r;
      int o = chunk*64 + ol;
      if (lane < 62){
        float2 v = *(float2*)&ytile[ol*130 + lane*2];
        *(float2*)&y[((size_t)b*On + o)*Ln + (size_t)i0*WP + lane*2] = v;
      }
    }
  }
}

// softmax v3: register-resident y (R6 win).
__global__ __launch_bounds__(256, 4) void k_softp(const float* __restrict__ y, ushort16* __restrict__ pb,
                                                  float* __restrict__ S1, float* __restrict__ S2){
  __shared__ float mpart[2][256], dpart[2][256];
  __shared__ float s1loc[128], s2loc[128];
  int b = blockIdx.x;
  int s = blockIdx.y;          // 0..30
  int i0 = s*2;
  int t = threadIdx.x;
  int j = t & 63;
  int og = t >> 6;
  if (t < 128){ s1loc[t] = 0.f; s2loc[t] = 0.f; }
  int je = j < WP ? j : (WP-1);
  const float* yb = y + ((size_t)b*On + og*32)*Ln + (size_t)i0*WP + je;
  float v0[32], v1[32];
  #pragma unroll
  for (int oi = 0; oi < 32; oi++){
    const float* yp = yb + (size_t)oi*Ln;
    v0[oi] = yp[0];
    v1[oi] = yp[WP];
  }
  float m0 = v0[0], m1 = v1[0];
  #pragma unroll
  for (int oi = 1; oi < 32; oi++){
    m0 = fmaxf(m0, v0[oi]);
    m1 = fmaxf(m1, v1[oi]);
  }
  float d0 = 0.f, d1 = 0.f;
  #pragma unroll
  for (int oi = 0; oi < 32; oi++){
    v0[oi] = __expf(v0[oi] - m0); d0 += v0[oi];
    v1[oi] = __expf(v1[oi] - m1); d1 += v1[oi];
  }
  mpart[0][t] = m0; dpart[0][t] = d0;
  mpart[1][t] = m1; dpart[1][t] = d1;
  __syncthreads();
  float scl[2];
  {
    float ml[2] = {m0, m1};
    #pragma unroll
    for (int r = 0; r < 2; r++){
      float ma = mpart[r][j],      mb = mpart[r][64+j];
      float mcc = mpart[r][128+j], md = mpart[r][192+j];
      float mm = fmaxf(fmaxf(ma, mb), fmaxf(mcc, md));
      float dd = dpart[r][j]*__expf(ma-mm) + dpart[r][64+j]*__expf(mb-mm)
               + dpart[r][128+j]*__expf(mcc-mm) + dpart[r][192+j]*__expf(md-mm);
      scl[r] = __expf(ml[r]-mm) / dd;
    }
  }
  bool act = j < WP;
  float sc0 = act ? scl[0] : 0.f;
  float sc1 = act ? scl[1] : 0.f;
  ushort16* ppb = pb + (((size_t)b*On + og*32)*HP + i0)*64 + j;
  #pragma unroll
  for (int oi = 0; oi < 32; oi++){
    float r0 = v0[oi]*sc0;
    float r1 = v1[oi]*sc1;
    float p0 = r0*r0, p1 = r1*r1;
    ushort16* pp = ppb + (size_t)oi*(HP*64);
    pp[0]  = (ushort16)bf16r(p0);
    pp[64] = (ushort16)bf16r(p1);
    float s1v = r0 + r1, s2v = p0 + p1;
    #pragma unroll
    for (int off = 32; off; off >>= 1){ s1v += __shfl_down(s1v, off); s2v += __shfl_down(s2v, off); }
    if (j == 0){ s1loc[og*32 + oi] += s1v; s2loc[og*32 + oi] += s2v; }
  }
  __syncthreads();
  if (t < 128){ atomicAdd(&S1[t], s1loc[t]); atomicAdd(&S2[t], s2loc[t]); }
}

// MFMA delta v8: R7 structure (2 blocks/CU proven) + conflict-free x-tile.
// R8 post-mortem: folding oh into the block dropped to 1 block/CU and doubled
// the serial chain -> 79us; REVERTED. R7's 13.25M conflict cycles came from
// x rows at 144B (per-cl read stride 432B ~ bank-stride 12, gcd4 -> 4-way).
// Fix: 128B x rows (stride == 0 banks) + granule slot = g ^ (row&7): 16 lanes
// -> 8 slots x 2 lanes = free 2-way, for d (b128) and e (b32) reads and writes.
// e for g==7 is element 64 (old zero-pad) -> constant 0, pad deleted.
#define DOKH2(av, dc, ec, off) { \
  U16 f0, f1, f2; \
  f0.q = dc; \
  f1.q = make_uint4((dc.x>>16)|(dc.y<<16), (dc.y>>16)|(dc.z<<16), \
                    (dc.z>>16)|(dc.w<<16), (dc.w>>16)|(ec<<16)); \
  f2.q = make_uint4(dc.y, dc.z, dc.w, ec); \
  acc[(off)+0] = __builtin_amdgcn_mfma_f32_16x16x32_bf16(av, f0.v, acc[(off)+0], 0, 0, 0); \
  acc[(off)+1] = __builtin_amdgcn_mfma_f32_16x16x32_bf16(av, f1.v, acc[(off)+1], 0, 0, 0); \
  acc[(off)+2] = __builtin_amdgcn_mfma_f32_16x16x32_bf16(av, f2.v, acc[(off)+2], 0, 0, 0); \
}

__global__ __launch_bounds__(512, 2) void k_deltam(const ushort16* __restrict__ xb,
                                                   const ushort16* __restrict__ pb,
                                                   float* __restrict__ G){
  // LDS: P 2set*64row*128B = 16384 | x 2set*48row*128B = 12288 (epilogue reuses 36864)
  __shared__ uint4 lds4[36864/16];
  char* ldsb = (char*)lds4;
  int t = threadIdx.x;
  int lane = t & 63;
  int wv = t >> 6;          // 0..7
  int mgl = wv & 3;
  int ih  = wv >> 2;
  int bx  = blockIdx.x;     // 0..7: ntk = bx&3, khalf = bx>>2
  int ntk = bx & 3;
  int khalf = bx >> 2;
  int b   = blockIdx.y;
  int oh  = blockIdx.z;
  int it0 = khalf*16;
  int nit = khalf ? 15 : 16;
  int cl = lane & 15;
  int quad = lane >> 4;

  // ---- P staging (R7-proven) ----
  int o128 = t >> 2;
  int sP = o128 >> 6;
  int oP = o128 & 63;
  int segP = t & 3;
  const ushort16* pbase = pb + ((size_t)b*On + oh*64 + oP)*(HP*64) + segP*16;
  int pIrow = sP*31 + it0;
  char* pwr = ldsb + (sP*64 + oP)*128;
  int psw0 = ((2*segP)     ^ (oP & 7)) << 4;
  int psw1 = ((2*segP + 1) ^ (oP & 7)) << 4;
  // ---- x staging: 128B rows, granule XOR swizzle ----
  int pX = t & 7;
  int r1 = t >> 3;
  int s1_ = (r1 >= 48) ? 1 : 0;
  int rr1 = r1 - s1_*48;
  int c1 = rr1/3, kh1 = rr1 - c1*3;
  int rr2 = (64 + (t >> 3)) - 48;
  int c2 = rr2/3, kh2 = rr2 - c2*3;
  const ushort16* xbb = xb + ((size_t)b*Cn + ntk*16)*(Hn*Wn) + pX*8;
  const ushort16* x1base = xbb + (size_t)c1*(Hn*Wn);
  const ushort16* x2base = xbb + (size_t)c2*(Hn*Wn);
  int x1Irow = s1_*31 + kh1 + it0;
  int x2Irow = 31 + kh2 + it0;
  char* x1wr = ldsb + 16384 + (s1_*48 + c1*3 + kh1)*128 + ((pX ^ ((c1*3+kh1)&7))<<4);
  char* x2wr = ldsb + 16384 + (48    + c2*3 + kh2)*128 + ((pX ^ ((c2*3+kh2)&7))<<4);

  const char* ptb = ldsb + ih*8192;
  const char* xtb = ldsb + 16384 + ih*6144;
  int orow = mgl*16 + cl;
  int o7 = cl & 7;

  floatx4 acc[9];
  #pragma unroll
  for (int nt = 0; nt < 9; nt++) acc[nt] = (floatx4){0.f, 0.f, 0.f, 0.f};
  union U16 { uint4 q; bf16x8 v; };

  uint4 pr0, pr1, xr0, xr1;
  {
    const ushort16* prow = pbase + (size_t)(pIrow + 0)*64;
    pr0 = *(const uint4*)(prow);
    pr1 = *(const uint4*)(prow + 8);
    xr0 = *(const uint4*)(x1base + (size_t)(x1Irow + 0)*Wn);
    if (t < 256) xr1 = *(const uint4*)(x2base + (size_t)(x2Irow + 0)*Wn);
  }

  for (int it = 0; it < nit; ++it){
    __syncthreads();
    *(uint4*)(pwr + psw0) = pr0;
    *(uint4*)(pwr + psw1) = pr1;
    *(uint4*)(x1wr) = xr0;
    if (t < 256) *(uint4*)(x2wr) = xr1;
    if (it < nit-1){
      const ushort16* prow = pbase + (size_t)(pIrow + it + 1)*64;
      pr0 = *(const uint4*)(prow);
      pr1 = *(const uint4*)(prow + 8);
      xr0 = *(const uint4*)(x1base + (size_t)(x1Irow + it + 1)*Wn);
      if (t < 256) xr1 = *(const uint4*)(x2base + (size_t)(x2Irow + it + 1)*Wn);
    }
    __syncthreads();
    #pragma unroll
    for (int sl = 0; sl < 2; sl++){
      U16 a;
      a.q = *(const uint4*)(ptb + orow*128 + (((sl*4 + quad) ^ o7) << 4));
      #pragma unroll
      for (int kh = 0; kh < 3; kh++){
        int row = cl*3 + kh;
        const char* rb = xtb + row*128;
        int r7x = row & 7;
        int g = sl*4 + quad;
        uint4 d = *(const uint4*)(rb + ((g ^ r7x) << 4));
        uint32 e = (g < 7) ? *(const uint32*)(rb + (((g+1) ^ r7x) << 4)) : 0u;
        DOKH2(a.v, d, e, kh*3)
      }
    }
  }

  __syncthreads();
  float* sc = (float*)ldsb;
  if (ih == 1){
    #pragma unroll
    for (int nt = 0; nt < 9; nt++)
      #pragma unroll
      for (int reg = 0; reg < 4; reg++)
        sc[(mgl*16 + quad*4 + reg)*144 + nt*16 + cl] = acc[nt][reg];
  }
  __syncthreads();
  if (ih == 0){
    float* Gq = G + (size_t)(b & 3)*GSZ;
    #pragma unroll
    for (int nt = 0; nt < 9; nt++)
      #pragma unroll
      for (int reg = 0; reg < 4; reg++){
        int ol = mgl*16 + quad*4 + reg;
        int og = oh*64 + ol;
        float v = acc[nt][reg] + sc[ol*144 + nt*16 + cl];
        atomicAdd(&Gq[(size_t)og*CKn + nt*64 + ntk*16 + cl], v);
      }
  }
}

__global__ __launch_bounds__(576) void k_finalm(const float* __restrict__ w, const float* __restrict__ G,
                                                const float* __restrict__ S1, const float* __restrict__ S2,
                                                float* __restrict__ dw){
  int o = blockIdx.x; int k = threadIdx.x;
  int c = k / 9;
  int q = k - c*9;
  float s1 = S1[o]; if (s1 == 0.f) s1 = 1.f;
  float g = 0.f;
  #pragma unroll
  for (int kq = 0; kq < KSB; kq++) g += G[(size_t)kq*GSZ + o*CKn + q*64 + c];
  dw[o*CKn + k] = (g - S2[o]*w[o*CKn + k]) / s1;
}

// ---------------- old fallback path ----------------
__global__ __launch_bounds__(256) void k_soft_old(const float* __restrict__ y, float* __restrict__ mbuf,
                                                  float* __restrict__ invdbuf, float* __restrict__ S1,
                                                  float* __restrict__ S2){
  __shared__ float s1loc[128], s2loc[128];
  int t = threadIdx.x;
  if (t < 128){ s1loc[t] = 0.f; s2loc[t] = 0.f; }
  __syncthreads();
  int b = blockIdx.x;
  int i = blockIdx.y*4 + (t >> 6);
  int j = t & 63;
  bool act = (i < 62) && (j < 62);
  const float* yp = y + (((size_t)b*On)*HP + (i < 62 ? i : 0))*WP + j;
  float mx = -3.0e38f;
  if (act){ for (int o = 0; o < On; o++) mx = fmaxf(mx, yp[(size_t)o*Ln]); }
  float den = 0.f;
  if (act){ for (int o = 0; o < On; o++) den += __expf(yp[(size_t)o*Ln] - mx); }
  float inv = act ? 1.f/den : 0.f;
  if (act){
    int pos = (b*HP + i)*WP + j;
    mbuf[pos] = mx; invdbuf[pos] = inv;
  }
  for (int o = 0; o < On; o++){
    float r = act ? __expf(yp[(size_t)o*Ln] - mx)*inv : 0.f;
    float s1v = r, s2v = r*r;
    #pragma unroll
    for (int off = 32; off; off >>= 1){ s1v += __shfl_down(s1v, off); s2v += __shfl_down(s2v, off); }
    if ((t & 63) == 0){ atomicAdd(&s1loc[o], s1v); atomicAdd(&s2loc[o], s2v); }
  }
  __syncthreads();
  if (t < 128){ atomicAdd(&S1[t], s1loc[t]); atomicAdd(&S2[t], s2loc[t]); }
}

__global__ __launch_bounds__(256) void k_delta_old(const float* __restrict__ x, const float* __restrict__ y,
                                                   const float* __restrict__ mbuf, const float* __restrict__ invdbuf,
                                                   float* __restrict__ G){
  __shared__ float planes[3][64][64];
  __shared__ float plds[16][64];
  int o0 = blockIdx.x * 16;
  int bs = blockIdx.y;
  int b = bs >> 2;
  int s = bs & 3;
  int i0 = s * 16;
  int nrows = (s == 3) ? 14 : 16;
  int t = threadIdx.x;
  int lane = t & 63;
  int w = t >> 6;
  int lc = t >> 2;
  int lw0 = (t & 3) << 4;
  const float* xb = x + (size_t)b*(Cn*Hn*Wn) + (size_t)lc*(Hn*Wn) + lw0;
  float acc[4][9];
  #pragma unroll
  for (int oi = 0; oi < 4; oi++)
    #pragma unroll
    for (int q = 0; q < 9; q++) acc[oi][q] = 0.f;
  #pragma unroll
  for (int pp = 0; pp < 2; pp++){
    int ih = i0 + pp;
    const float* src = xb + (size_t)ih*Wn;
    #pragma unroll
    for (int q = 0; q < 16; q++) planes[ih % 3][lw0 + q][lc] = src[q];
  }
  for (int ii = 0; ii < nrows; ii++){
    int i = i0 + ii;
    {
      int ih = i + 2;
      const float* src = xb + (size_t)ih*Wn;
      #pragma unroll
      for (int q = 0; q < 16; q++) planes[ih % 3][lw0 + q][lc] = src[q];
    }
    int R = b*HP + i;
    #pragma unroll
    for (int oi = 0; oi < 4; oi++){
      int o = o0 + w*4 + oi;
      float p = 0.f;
      if (lane < WP){
        int pos = R*WP + lane;
        float yv = y[(((size_t)b*On + o)*HP + i)*WP + lane];
        float r = __expf(yv - mbuf[pos]) * invdbuf[pos];
        p = r*r;
      }
      plds[w*4 + oi][lane] = p;
    }
    __syncthreads();
    int c = lane;
    int s0 = i % 3, s1 = (i+1) % 3, s2g = (i+2) % 3;
    #pragma unroll 1
    for (int jj0 = 0; jj0 < 56; jj0 += 8){
      float xv[3][12];
      #pragma unroll
      for (int q = 0; q < 12; q++){
        xv[0][q] = planes[s0][jj0+q][c];
        xv[1][q] = planes[s1][jj0+q][c];
        xv[2][q] = planes[s2g][jj0+q][c];
      }
      #pragma unroll
      for (int oi = 0; oi < 4; oi++){
        float4 pa = *(const float4*)&plds[w*4+oi][jj0];
        float4 pbq = *(const float4*)&plds[w*4+oi][jj0+4];
        float pv[8] = {pa.x,pa.y,pa.z,pa.w,pbq.x,pbq.y,pbq.z,pbq.w};
        #pragma unroll
        for (int kh = 0; kh < 3; kh++)
          #pragma unroll
          for (int kw = 0; kw < 3; kw++)
            #pragma unroll
            for (int dj = 0; dj < 8; dj++)
              acc[oi][kh*3+kw] += pv[dj]*xv[kh][dj+kw];
      }
    }
    {
      float xv[3][12];
      #pragma unroll
      for (int q = 0; q < 12; q++){
        bool ok = (56 + q) < 64;
        xv[0][q] = ok ? planes[s0][56+q][c] : 0.f;
        xv[1][q] = ok ? planes[s1][56+q][c] : 0.f;
        xv[2][q] = ok ? planes[s2g][56+q][c] : 0.f;
      }
      #pragma unroll
      for (int oi = 0; oi < 4; oi++){
        float4 pa = *(const float4*)&plds[w*4+oi][56];
        float4 pbq = *(const float4*)&plds[w*4+oi][60];
        float pv[8] = {pa.x,pa.y,pa.z,pa.w,pbq.x,pbq.y,pbq.z,pbq.w};
        #pragma unroll
        for (int kh = 0; kh < 3; kh++)
          #pragma unroll
          for (int kw = 0; kw < 3; kw++)
            #pragma unroll
            for (int dj = 0; dj < 8; dj++)
              acc[oi][kh*3+kw] += pv[dj]*xv[kh][dj+kw];
      }
    }
    __syncthreads();
  }
  #pragma unroll
  for (int oi = 0; oi < 4; oi++){
    float* Gr = G + (size_t)(o0 + w*4 + oi)*CKn + lane*9;
    #pragma unroll
    for (int q = 0; q < 9; q++) atomicAdd(&Gr[q], acc[oi][q]);
  }
}

__global__ __launch_bounds__(576) void k_final_old(const float* __restrict__ w, const float* __restrict__ G,
                                                   const float* __restrict__ S1, const float* __restrict__ S2,
                                                   float* __restrict__ dw){
  int o = blockIdx.x; int k = threadIdx.x;
  float s1 = S1[o]; if (s1 == 0.f) s1 = 1.f;
  dw[o*CKn + k] = (G[o*CKn + k] - S2[o]*w[o*CKn + k]) / s1;
}

extern "C" void kernel_launch(void* const* d_in, const int* in_sizes, int n_in,
                              void* d_out, int out_size, void* d_ws, size_t ws_size,
                              hipStream_t stream){
  const float* x    = (const float*)d_in[0];
  const float* w    = (const float*)d_in[1];
  const float* bias = (const float*)d_in[2];
  float* y  = (float*)d_out;
  float* dw = (float*)d_out + Y_ELEMS;
  float* ws = (float*)d_ws;

  if (ws_size >= WS_NEED){
    float* S1 = ws + NS1;
    float* S2 = ws + NS2;
    float* G  = ws + NG;
    ushort16* wnb = (ushort16*)(ws + NWNB);
    ushort16* xb  = (ushort16*)(ws + NXB);
    ushort16* pb  = (ushort16*)(ws + NPB);
    k_normxb<<<dim3(8320),    dim3(256), 0, stream>>>(w, wnb, S1, S2, G, x, xb);
    k_convm <<<dim3(31, Bn),  dim3(256), 0, stream>>>(x, wnb, bias, y);
    k_softp <<<dim3(Bn, 31),  dim3(256), 0, stream>>>(y, pb, S1, S2);
    k_deltam<<<dim3(8, Bn, 2), dim3(512), 0, stream>>>(xb, pb, G);
    k_finalm<<<dim3(On),      dim3(CKn), 0, stream>>>(w, G, S1, S2, dw);
  } else {
    float* S1   = ws + 73728;
    float* S2   = ws + 73856;
    float* G    = ws + 73984;
    float* mbuf = ws + 147712;
    float* invd = ws + 270720;
    ushort16* wnb = (ushort16*)(ws + 393728);
    k_norm     <<<dim3(On),      dim3(256), 0, stream>>>(w, wnb, S1, S2, G, 1);
    k_convm    <<<dim3(31, Bn),  dim3(256), 0, stream>>>(x, wnb, bias, y);
    k_soft_old <<<dim3(Bn, 16),  dim3(256), 0, stream>>>(y, mbuf, invd, S1, S2);
    k_delta_old<<<dim3(8, Bn*4), dim3(256), 0, stream>>>(x, y, mbuf, invd, G);
    k_final_old<<<dim3(On),      dim3(CKn), 0, stream>>>(w, G, S1, S2, dw);
  }
}